// Round 2
// baseline (251.451 us; speedup 1.0000x reference)
//
#include <hip/hip_runtime.h>
#include <hip/hip_bf16.h>

typedef __hip_bfloat16 bf16;

#define NNODES 768
#define NEPS   767   // edges per sender

// ---- module-global scratch (avoids any dependence on ws_size) ----
#define OFF_EMB0 0
#define OFF_SA1  24576
#define OFF_SB1  49152
#define OFF_MSG1 73728
#define OFF_EMB1 98304
#define OFF_SA2  147456
#define OFF_SB2  172032
#define OFF_MSG2 196608
#define OFF_EMB2 221184
__device__ float g_ws[270336];
__device__ int   g_flag;   // 1 = inputs are float32, 0 = inputs are bf16

__device__ __forceinline__ float b2f(bf16 v){ return __bfloat162float(v); }
__device__ __forceinline__ float LD(const void* p, int i, int f32){
  return f32 ? ((const float*)p)[i] : b2f(((const bf16*)p)[i]);
}
__device__ __forceinline__ void ST(void* p, int i, float v, int f32){
  if (f32) ((float*)p)[i] = v; else ((bf16*)p)[i] = __float2bfloat16(v);
}
__device__ __forceinline__ float fast_rcp(float x){ return __builtin_amdgcn_rcpf(x); }
__device__ __forceinline__ float silu_f(float p){ return p * fast_rcp(1.f + __expf(-p)); }

// ---------------- K0: dtype detection ----------------
// f[0] = pi. fp32 read gives 3.14159; bf16-pair read decodes to ~6.289.
__global__ void k_detect(const void* __restrict__ f){
  float v = ((const float*)f)[0];
  g_flag = (fabsf(v - 3.14159265f) < 0.01f) ? 1 : 0;
}

// ---------------- K1: emb0 gather + SA1/SB1 precompute ----------------
__global__ void k_prep1(const int* __restrict__ charges, const void* __restrict__ etab,
                        const void* __restrict__ w0){
  int i = blockIdx.x, j = threadIdx.x;            // 32 threads
  int isf = g_flag;
  __shared__ float row[32];
  int c = charges[i];
  float v = LD(etab, c*32 + j, isf);
  g_ws[OFF_EMB0 + i*32 + j] = v;
  row[j] = v;
  __syncthreads();
  float sa = 0.f, sb = 0.f;
  #pragma unroll
  for (int k = 0; k < 32; k++){
    float rv = row[k];
    sa = fmaf(rv, LD(w0, k*32 + j, isf),      sa);
    sb = fmaf(rv, LD(w0, (32+k)*32 + j, isf), sb);
  }
  g_ws[OFF_SA1 + i*32 + j] = sa;
  g_ws[OFF_SB1 + i*32 + j] = sb;
}

// ---------------- K2/K4: fused edge pass (RBF + edge MLP + segment mean) ----------------
// pre_e = SA[i] + SB[r] + rbf_e @ w0e + b0 ;  msg[i] = (sum_e silu(pre_e)) @ w1 / 767 + b1
__launch_bounds__(256, 2)
__global__ void k_edge(const void* __restrict__ nuclei, const void* __restrict__ fvec,
                       int sa_off, int sb_off,
                       const void* __restrict__ w0e, int w0e_off,
                       const void* __restrict__ b0,
                       const void* __restrict__ w1, const void* __restrict__ b1,
                       int msg_off)
{
  __shared__ __align__(16) float pos[NNODES*3];
  __shared__ __align__(16) float w0eL[1024];
  __shared__ __align__(16) float w1L[1024];
  __shared__ __align__(16) float preB[32];
  __shared__ __align__(16) float f01[32];
  __shared__ __align__(16) float hbuf[256*33 + 32];

  int i = blockIdx.x, t = threadIdx.x;
  int isf = g_flag;
  const float* SA = g_ws + sa_off;
  const float* SB = g_ws + sb_off;

  for (int idx = t; idx < NNODES*3; idx += 256) pos[idx] = LD(nuclei, idx, isf);
  for (int idx = t; idx < 1024; idx += 256){
    w0eL[idx] = LD(w0e, w0e_off + idx, isf);
    w1L[idx]  = LD(w1, idx, isf);
  }
  if (t < 32){ preB[t] = SA[i*32 + t] + LD(b0, t, isf); f01[t] = LD(fvec, t, isf) * 0.1f; }
  __syncthreads();

  float px = pos[i*3], py = pos[i*3+1], pz = pos[i*3+2];

  int   rs[3]; float xs[3], sc[3];
  #pragma unroll
  for (int s = 0; s < 3; s++){
    int el = t + 256*s;
    if (el >= NEPS) el = 0;                 // dummy slot (masked later)
    int e = i*NEPS + el;
    int q = e / 768;
    int r = e - q*768 + q + 1;
    if (r >= 768) r -= 768;
    rs[s] = r;
    float dx = px - pos[r*3], dy = py - pos[r*3+1], dz = pz - pos[r*3+2];
    float d = sqrtf(fmaf(dx, dx, fmaf(dy, dy, dz*dz)));
    xs[s] = d + 1e-8f;
    sc[s] = 0.44721359549995793f * fast_rcp(xs[s]);   // sqrt(2/10)/x
  }
  float v2 = (t + 512 < NEPS) ? 1.f : 0.f;  // only the 3rd slot can be invalid

  float pre[3][32];
  #pragma unroll
  for (int s = 0; s < 3; s++){
    const float* sbr = SB + rs[s]*32;
    #pragma unroll
    for (int j = 0; j < 32; j++) pre[s][j] = preB[j] + sbr[j];
  }

  #pragma unroll 2
  for (int k = 0; k < 32; k++){
    float fk = f01[k];
    float rb[3];
    #pragma unroll
    for (int s = 0; s < 3; s++) rb[s] = sc[s] * __sinf(fk * xs[s]);
    const float4* wrow = (const float4*)(w0eL + (k << 5));
    #pragma unroll
    for (int j4 = 0; j4 < 8; j4++){
      float4 w = wrow[j4];
      #pragma unroll
      for (int s = 0; s < 3; s++){
        pre[s][4*j4+0] = fmaf(rb[s], w.x, pre[s][4*j4+0]);
        pre[s][4*j4+1] = fmaf(rb[s], w.y, pre[s][4*j4+1]);
        pre[s][4*j4+2] = fmaf(rb[s], w.z, pre[s][4*j4+2]);
        pre[s][4*j4+3] = fmaf(rb[s], w.w, pre[s][4*j4+3]);
      }
    }
  }

  // silu + per-thread edge sum (mask dummy 3rd edge)
  float hsum[32];
  #pragma unroll
  for (int j = 0; j < 32; j++){
    float s0 = silu_f(pre[0][j]);
    float s1 = silu_f(pre[1][j]);
    float s2 = silu_f(pre[2][j]);
    hsum[j] = s0 + s1 + v2 * s2;
  }

  // block reduction of hsum over 256 threads (stride-33 -> conflict-free)
  #pragma unroll
  for (int j = 0; j < 32; j++) hbuf[t*33 + j] = hsum[j];
  __syncthreads();
  if (t < 32){
    float ssum = 0.f;
    for (int r2 = 0; r2 < 256; r2++) ssum += hbuf[r2*33 + t];
    hbuf[256*33 + t] = ssum;
  }
  __syncthreads();
  if (t < 32){
    float yv = 0.f;
    #pragma unroll
    for (int m = 0; m < 32; m++) yv = fmaf(hbuf[256*33 + m], w1L[m*32 + t], yv);
    g_ws[msg_off + i*32 + t] = yv * (1.f/767.f) + LD(b1, t, isf);
  }
}

// ---------------- K3: update MLP 1 + SA2/SB2 precompute ----------------
__global__ void k_upd1(const void* __restrict__ w0, const void* __restrict__ b0v,
                       const void* __restrict__ w1, const void* __restrict__ b1v,
                       const void* __restrict__ mp2w0){
  int i = blockIdx.x, t = threadIdx.x;           // 64 threads
  int isf = g_flag;
  __shared__ float cat[64], hL[64], e1L[64];
  cat[t] = (t < 32) ? g_ws[OFF_EMB0 + i*32 + t] : g_ws[OFF_MSG1 + i*32 + (t - 32)];
  __syncthreads();
  float a = LD(b0v, t, isf);
  #pragma unroll 4
  for (int k = 0; k < 64; k++) a = fmaf(cat[k], LD(w0, k*64 + t, isf), a);
  hL[t] = silu_f(a);
  __syncthreads();
  float y = LD(b1v, t, isf);
  #pragma unroll 4
  for (int k = 0; k < 64; k++) y = fmaf(hL[k], LD(w1, k*64 + t, isf), y);
  g_ws[OFF_EMB1 + i*64 + t] = y;
  e1L[t] = y;
  __syncthreads();
  int col = t & 31;
  int wbase = (t < 32) ? 0 : 64*32;
  float s2 = 0.f;
  #pragma unroll 4
  for (int k = 0; k < 64; k++) s2 = fmaf(e1L[k], LD(mp2w0, wbase + k*32 + col, isf), s2);
  if (t < 32) g_ws[OFF_SA2 + i*32 + col] = s2;
  else        g_ws[OFF_SB2 + i*32 + col] = s2;
}

// ---------------- K5: update MLP 2 + residual + node_out + emb2 store ----------------
__global__ void k_upd2(const void* __restrict__ w0, const void* __restrict__ b0v,
                       const void* __restrict__ w1, const void* __restrict__ b1v,
                       const void* __restrict__ no_w0, const void* __restrict__ no_b0,
                       const void* __restrict__ no_w1, const void* __restrict__ no_embed,
                       const int* __restrict__ charges, void* __restrict__ out){
  int i = blockIdx.x, t = threadIdx.x;           // 64 threads
  int isf = g_flag;
  __shared__ float cat[96], hL[64], agg[160], h3[3];
  cat[t] = g_ws[OFF_EMB1 + i*64 + t];
  if (t < 32){ cat[64 + t] = g_ws[OFF_MSG2 + i*32 + t]; agg[t] = g_ws[OFF_EMB0 + i*32 + t]; }
  __syncthreads();
  float a = LD(b0v, t, isf);
  #pragma unroll 4
  for (int k = 0; k < 96; k++) a = fmaf(cat[k], LD(w0, k*64 + t, isf), a);
  hL[t] = silu_f(a);
  __syncthreads();
  float y = LD(b1v, t, isf);
  #pragma unroll 4
  for (int k = 0; k < 64; k++) y = fmaf(hL[k], LD(w1, k*64 + t, isf), y);
  float e2 = cat[t] + y;                          // residual
  agg[32 + t] = cat[t];
  agg[96 + t] = e2;
  g_ws[OFF_EMB2 + i*64 + t] = e2;
  __syncthreads();
  if (t < 3){
    float p = LD(no_b0, t, isf);
    for (int k = 0; k < 160; k++) p = fmaf(agg[k], LD(no_w0, k*3 + t, isf), p);
    h3[t] = silu_f(p);
  }
  __syncthreads();
  if (t < 3){
    float o = 0.f;
    #pragma unroll
    for (int m = 0; m < 3; m++) o = fmaf(h3[m], LD(no_w1, m*3 + t, isf), o);
    o += LD(no_embed, charges[i]*3 + t, isf);
    ST(out, i*3 + t, o, isf);
  }
}

// ---------------- K6: global readout (column-sum over nodes, no atomics) ----------------
__global__ void k_glob(const void* __restrict__ go_w0, const void* __restrict__ go_b0,
                       const void* __restrict__ go_w1, const void* __restrict__ go_b1,
                       void* __restrict__ out){
  int t = threadIdx.x;                            // 256 threads
  int isf = g_flag;
  __shared__ float red[256];
  float s = 0.f;
  if (t < 160){
    if (t < 32){
      for (int i = 0; i < NNODES; i++) s += g_ws[OFF_EMB0 + i*32 + t];
    } else if (t < 96){
      int c = t - 32;
      for (int i = 0; i < NNODES; i++) s += g_ws[OFF_EMB1 + i*64 + c];
    } else {
      int c = t - 96;
      for (int i = 0; i < NNODES; i++) s += g_ws[OFF_EMB2 + i*64 + c];
    }
    s = (s * (1.f/768.f)) * LD(go_w0, t, isf);
  }
  red[t] = s;
  __syncthreads();
  if (t == 0){
    float tot = 0.f;
    for (int k = 0; k < 256; k++) tot += red[k];
    float h = silu_f(tot + LD(go_b0, 0, isf));
    ST(out, 2304, h * LD(go_w1, 0, isf) + LD(go_b1, 0, isf), isf);
  }
}

extern "C" void kernel_launch(void* const* d_in, const int* in_sizes, int n_in,
                              void* d_out, int out_size, void* d_ws, size_t ws_size,
                              hipStream_t stream) {
  const void* nuclei  = d_in[0];
  const int*  charges = (const int*)d_in[1];
  const void* fvec    = d_in[2];
  const void* etab    = d_in[3];
  const void* mp1_w0  = d_in[4];
  const void* mp1_b0  = d_in[5];
  const void* mp1_w1  = d_in[6];
  const void* mp1_b1  = d_in[7];
  const void* up1_w0  = d_in[8];
  const void* up1_b0  = d_in[9];
  const void* up1_w1  = d_in[10];
  const void* up1_b1  = d_in[11];
  const void* mp2_w0  = d_in[12];
  const void* mp2_b0  = d_in[13];
  const void* mp2_w1  = d_in[14];
  const void* mp2_b1  = d_in[15];
  const void* up2_w0  = d_in[16];
  const void* up2_b0  = d_in[17];
  const void* up2_w1  = d_in[18];
  const void* up2_b1  = d_in[19];
  const void* no_w0   = d_in[20];
  const void* no_b0   = d_in[21];
  const void* no_w1   = d_in[22];
  const void* no_emb  = d_in[23];
  const void* go_w0   = d_in[24];
  const void* go_b0   = d_in[25];
  const void* go_w1   = d_in[26];
  const void* go_b1   = d_in[27];

  k_detect<<<1, 1, 0, stream>>>(fvec);
  k_prep1<<<NNODES, 32, 0, stream>>>(charges, etab, mp1_w0);
  k_edge <<<NNODES, 256, 0, stream>>>(nuclei, fvec, OFF_SA1, OFF_SB1,
                                      mp1_w0, 64*32, mp1_b0, mp1_w1, mp1_b1, OFF_MSG1);
  k_upd1 <<<NNODES, 64, 0, stream>>>(up1_w0, up1_b0, up1_w1, up1_b1, mp2_w0);
  k_edge <<<NNODES, 256, 0, stream>>>(nuclei, fvec, OFF_SA2, OFF_SB2,
                                      mp2_w0, 128*32, mp2_b0, mp2_w1, mp2_b1, OFF_MSG2);
  k_upd2 <<<NNODES, 64, 0, stream>>>(up2_w0, up2_b0, up2_w1, up2_b1,
                                     no_w0, no_b0, no_w1, no_emb, charges, d_out);
  k_glob <<<1, 256, 0, stream>>>(go_w0, go_b0, go_w1, go_b1, d_out);
}

// Round 3
// 232.207 us; speedup vs baseline: 1.0829x; 1.0829x over previous
//
#include <hip/hip_runtime.h>
#include <hip/hip_bf16.h>

typedef __hip_bfloat16 bf16;
typedef __attribute__((ext_vector_type(8))) short short8;
typedef __attribute__((ext_vector_type(4))) float float4v;

#define NN   768
#define NEPS 767

// g_ws layout (floats)
#define OFF_EMB0 0
#define OFF_SA1  24576
#define OFF_SB1  49152
#define OFF_MSG1 73728
#define OFF_EMB1 98304
#define OFF_SA2  147456
#define OFF_SB2  172032
#define OFF_MSG2 196608
__device__ float g_ws[221184];
__device__ float g_agg[160];
__device__ int   g_cnt;

__device__ __forceinline__ float b2f(bf16 v){ return __bfloat162float(v); }
__device__ __forceinline__ float LD(const void* p, int i, int f32){
  return f32 ? ((const float*)p)[i] : b2f(((const bf16*)p)[i]);
}
__device__ __forceinline__ void ST(void* p, int i, float v, int f32){
  if (f32) ((float*)p)[i] = v; else ((bf16*)p)[i] = __float2bfloat16(v);
}
__device__ __forceinline__ int detect_f32(const void* f){
  float v = ((const float*)f)[0];
  return (fabsf(v - 3.14159265f) < 0.01f) ? 1 : 0;
}
__device__ __forceinline__ float fast_rcp(float x){ return __builtin_amdgcn_rcpf(x); }
__device__ __forceinline__ float silu_f(float p){ return p * fast_rcp(1.f + __expf(-p)); }
__device__ __forceinline__ unsigned short rne_bf16(float x){
  unsigned int b = __float_as_uint(x);
  return (unsigned short)((b + 0x7fffu + ((b >> 16) & 1u)) >> 16);
}
__device__ __forceinline__ int recv_of(int e){
  int q = e / 768;
  int r = e - q*768 + q + 1;
  if (r >= 768) r -= 768;
  return r;
}

// ---------------- K1: emb0 gather + SA1/SB1 + zero agg/cnt ----------------
// 96 blocks x 256 threads, 8 nodes/block
__global__ void k_prep1(const int* __restrict__ charges, const void* __restrict__ etab,
                        const void* __restrict__ w0, const void* __restrict__ fvec){
  int t = threadIdx.x;
  int isf = detect_f32(fvec);
  int node = blockIdx.x*8 + (t >> 5);
  int col  = t & 31;
  __shared__ float w0L[2048];
  __shared__ float rowL[8][32];
  for (int idx = t; idx < 2048; idx += 256) w0L[idx] = LD(w0, idx, isf);
  if (blockIdx.x == 0){
    if (t < 160) g_agg[t] = 0.f;
    if (t == 255) g_cnt = 0;
  }
  int c = charges[node];
  float v = LD(etab, c*32 + col, isf);
  g_ws[OFF_EMB0 + node*32 + col] = v;
  rowL[t >> 5][col] = v;
  __syncthreads();
  int nd = t >> 5;
  float sa = 0.f, sb = 0.f;
  #pragma unroll
  for (int k = 0; k < 32; k++){
    float rv = rowL[nd][k];
    sa = fmaf(rv, w0L[k*32 + col],        sa);
    sb = fmaf(rv, w0L[(32+k)*32 + col],   sb);
  }
  g_ws[OFF_SA1 + node*32 + col] = sa;
  g_ws[OFF_SB1 + node*32 + col] = sb;
}

// ---------------- K2/K4: MFMA edge pass ----------------
// block = node i, 256 threads (4 waves), 48 tiles of 16 edges
__launch_bounds__(256)
__global__ void k_edge(const void* __restrict__ nuclei, const void* __restrict__ fvec,
                       int sa_off, int sb_off,
                       const void* __restrict__ w0e, int w0e_off,
                       const void* __restrict__ b0,
                       const void* __restrict__ w1, const void* __restrict__ b1,
                       int msg_off)
{
  __shared__ __align__(16) float pos[NN*3];
  __shared__ float wsum[4][32];
  __shared__ float hsumL[32];

  int i = blockIdx.x, t = threadIdx.x;
  int w = t >> 6, lane = t & 63, q = lane >> 4, c = lane & 15;
  int isf = detect_f32(fvec);
  const float* SA = g_ws + sa_off;
  const float* SB = g_ws + sb_off;

  for (int idx = t; idx < NN*3; idx += 256) pos[idx] = LD(nuclei, idx, isf);

  // B fragments: b[j] = w0e[q*8+j][c] (cols 0-15) / [16+c] (cols 16-31)
  short8 bf0, bf1;
  #pragma unroll
  for (int j = 0; j < 8; j++){
    int row = q*8 + j;
    bf0[j] = (short)rne_bf16(LD(w0e, w0e_off + row*32 + c,      isf));
    bf1[j] = (short)rne_bf16(LD(w0e, w0e_off + row*32 + 16 + c, isf));
  }
  float preB0 = SA[i*32 + c]      + LD(b0, c,      isf);
  float preB1 = SA[i*32 + 16 + c] + LD(b0, 16 + c, isf);
  float fj[8];
  #pragma unroll
  for (int j = 0; j < 8; j++) fj[j] = LD(fvec, q*8 + j, isf) * 0.1f;
  __syncthreads();

  float px = pos[i*3], py = pos[i*3+1], pz = pos[i*3+2];
  float sum0 = 0.f, sum1 = 0.f;

  for (int tl = w; tl < 48; tl += 4){
    // A fragment: edge m = c, k = q*8+j
    int el = tl*16 + c;
    int r  = recv_of(i*NEPS + el);
    float dx = px - pos[r*3], dy = py - pos[r*3+1], dz = pz - pos[r*3+2];
    float d  = sqrtf(fmaf(dx, dx, fmaf(dy, dy, dz*dz)));
    float xs = d + 1e-8f;
    float sc = 0.44721359549995793f * fast_rcp(xs);
    short8 af;
    #pragma unroll
    for (int j = 0; j < 8; j++) af[j] = (short)rne_bf16(sc * __sinf(fj[j]*xs));

    float4v z = {0.f, 0.f, 0.f, 0.f};
    float4v a0 = __builtin_amdgcn_mfma_f32_16x16x32_bf16(af, bf0, z, 0, 0, 0);
    float4v a1 = __builtin_amdgcn_mfma_f32_16x16x32_bf16(af, bf1, z, 0, 0, 0);

    // C layout: row(edge) = q*4+p, col = c
    #pragma unroll
    for (int p = 0; p < 4; p++){
      int el2 = tl*16 + q*4 + p;
      if (el2 < NEPS){
        int r2 = recv_of(i*NEPS + el2);
        float v0 = a0[p] + preB0 + SB[r2*32 + c];
        float v1 = a1[p] + preB1 + SB[r2*32 + 16 + c];
        sum0 += silu_f(v0);
        sum1 += silu_f(v1);
      }
    }
  }
  // reduce across quads (lanes with same c)
  sum0 += __shfl_xor(sum0, 16); sum0 += __shfl_xor(sum0, 32);
  sum1 += __shfl_xor(sum1, 16); sum1 += __shfl_xor(sum1, 32);
  if (lane < 16){ wsum[w][lane] = sum0; wsum[w][16 + lane] = sum1; }
  __syncthreads();
  if (t < 32) hsumL[t] = wsum[0][t] + wsum[1][t] + wsum[2][t] + wsum[3][t];
  __syncthreads();
  if (t < 32){
    float y = 0.f;
    #pragma unroll
    for (int m = 0; m < 32; m++) y = fmaf(hsumL[m], LD(w1, m*32 + t, isf), y);
    g_ws[msg_off + i*32 + t] = y * (1.f/767.f) + LD(b1, t, isf);
  }
}

// ---------------- K3: update MLP 1 + SA2/SB2 ----------------
// 192 blocks x 256 threads, 4 nodes/block
__global__ void k_upd1(const void* __restrict__ w0, const void* __restrict__ b0v,
                       const void* __restrict__ w1, const void* __restrict__ b1v,
                       const void* __restrict__ mp2w0, const void* __restrict__ fvec){
  int t = threadIdx.x;
  int isf = detect_f32(fvec);
  int nd = t >> 6, col = t & 63;
  int node = blockIdx.x*4 + nd;
  __shared__ float w0L[4096], w1L[4096], m2L[4096];
  __shared__ float catL[4][64], hLL[4][64], e1LL[4][64];
  for (int idx = t; idx < 12288; idx += 256){
    float v;
    if (idx < 4096)      { v = LD(w0, idx, isf);          w0L[idx] = v; }
    else if (idx < 8192) { v = LD(w1, idx - 4096, isf);   w1L[idx - 4096] = v; }
    else                 { v = LD(mp2w0, idx - 8192, isf); m2L[idx - 8192] = v; }
  }
  catL[nd][col] = (col < 32) ? g_ws[OFF_EMB0 + node*32 + col]
                             : g_ws[OFF_MSG1 + node*32 + col - 32];
  __syncthreads();
  float a = LD(b0v, col, isf);
  #pragma unroll 8
  for (int k = 0; k < 64; k++) a = fmaf(catL[nd][k], w0L[k*64 + col], a);
  hLL[nd][col] = silu_f(a);
  __syncthreads();
  float y = LD(b1v, col, isf);
  #pragma unroll 8
  for (int k = 0; k < 64; k++) y = fmaf(hLL[nd][k], w1L[k*64 + col], y);
  g_ws[OFF_EMB1 + node*64 + col] = y;
  e1LL[nd][col] = y;
  __syncthreads();
  int c32 = col & 31;
  int base = (col < 32) ? 0 : 2048;   // rows 0-63 -> SA2, rows 64-127 -> SB2
  float s2 = 0.f;
  #pragma unroll 8
  for (int k = 0; k < 64; k++) s2 = fmaf(e1LL[nd][k], m2L[base + k*32 + c32], s2);
  if (col < 32) g_ws[OFF_SA2 + node*32 + c32] = s2;
  else          g_ws[OFF_SB2 + node*32 + c32] = s2;
}

// ---------------- K5: update MLP 2 + residual + node_out + global readout ----------------
// 192 blocks x 256 threads, 4 nodes/block; last block does the global MLP
__global__ void k_upd2(const void* __restrict__ w0, const void* __restrict__ b0v,
                       const void* __restrict__ w1, const void* __restrict__ b1v,
                       const void* __restrict__ no_w0, const void* __restrict__ no_b0,
                       const void* __restrict__ no_w1, const void* __restrict__ no_embed,
                       const void* __restrict__ go_w0, const void* __restrict__ go_b0,
                       const void* __restrict__ go_w1, const void* __restrict__ go_b1,
                       const int* __restrict__ charges, const void* __restrict__ fvec,
                       void* __restrict__ out){
  int t = threadIdx.x;
  int isf = detect_f32(fvec);
  int nd = t >> 6, col = t & 63;
  int node = blockIdx.x*4 + nd;
  __shared__ float w0L[6144], w1L[4096];
  __shared__ float catL[4][96], hLL[4][64], aggL[4][160], h3L[4][3];
  __shared__ float red[256];
  __shared__ int lastL;
  for (int idx = t; idx < 10240; idx += 256){
    if (idx < 6144) w0L[idx] = LD(w0, idx, isf);
    else            w1L[idx - 6144] = LD(w1, idx - 6144, isf);
  }
  catL[nd][col] = g_ws[OFF_EMB1 + node*64 + col];
  if (col < 32){
    catL[nd][64 + col] = g_ws[OFF_MSG2 + node*32 + col];
    aggL[nd][col]      = g_ws[OFF_EMB0 + node*32 + col];
  }
  __syncthreads();
  float a = LD(b0v, col, isf);
  #pragma unroll 8
  for (int k = 0; k < 96; k++) a = fmaf(catL[nd][k], w0L[k*64 + col], a);
  hLL[nd][col] = silu_f(a);
  __syncthreads();
  float y = LD(b1v, col, isf);
  #pragma unroll 8
  for (int k = 0; k < 64; k++) y = fmaf(hLL[nd][k], w1L[k*64 + col], y);
  float e2 = catL[nd][col] + y;       // residual
  aggL[nd][32 + col] = catL[nd][col]; // emb1
  aggL[nd][96 + col] = e2;            // emb2
  __syncthreads();
  if (col < 3){
    float p = LD(no_b0, col, isf);
    for (int k = 0; k < 160; k++) p = fmaf(aggL[nd][k], LD(no_w0, k*3 + col, isf), p);
    h3L[nd][col] = silu_f(p);
  }
  __syncthreads();
  if (col < 3){
    float o = 0.f;
    #pragma unroll
    for (int m = 0; m < 3; m++) o = fmaf(h3L[nd][m], LD(no_w1, m*3 + col, isf), o);
    o += LD(no_embed, charges[node]*3 + col, isf);
    ST(out, node*3 + col, o, isf);
  }
  // block partial of agg -> global atomics
  if (t < 160){
    float s = aggL[0][t] + aggL[1][t] + aggL[2][t] + aggL[3][t];
    atomicAdd(&g_agg[t], s);
  }
  __threadfence();
  __syncthreads();
  if (t == 0){
    int old = atomicAdd(&g_cnt, 1);
    lastL = (old == 191) ? 1 : 0;
  }
  __syncthreads();
  if (lastL){
    float v = 0.f;
    if (t < 160) v = atomicAdd(&g_agg[t], 0.f) * (1.f/768.f) * LD(go_w0, t, isf);
    red[t] = v;
    __syncthreads();
    if (t == 0){
      float tot = 0.f;
      for (int k = 0; k < 160; k++) tot += red[k];
      float h = silu_f(tot + LD(go_b0, 0, isf));
      ST(out, 2304, h * LD(go_w1, 0, isf) + LD(go_b1, 0, isf), isf);
    }
  }
}

extern "C" void kernel_launch(void* const* d_in, const int* in_sizes, int n_in,
                              void* d_out, int out_size, void* d_ws, size_t ws_size,
                              hipStream_t stream) {
  const void* nuclei  = d_in[0];
  const int*  charges = (const int*)d_in[1];
  const void* fvec    = d_in[2];
  const void* etab    = d_in[3];
  const void* mp1_w0  = d_in[4];
  const void* mp1_b0  = d_in[5];
  const void* mp1_w1  = d_in[6];
  const void* mp1_b1  = d_in[7];
  const void* up1_w0  = d_in[8];
  const void* up1_b0  = d_in[9];
  const void* up1_w1  = d_in[10];
  const void* up1_b1  = d_in[11];
  const void* mp2_w0  = d_in[12];
  const void* mp2_b0  = d_in[13];
  const void* mp2_w1  = d_in[14];
  const void* mp2_b1  = d_in[15];
  const void* up2_w0  = d_in[16];
  const void* up2_b0  = d_in[17];
  const void* up2_w1  = d_in[18];
  const void* up2_b1  = d_in[19];
  const void* no_w0   = d_in[20];
  const void* no_b0   = d_in[21];
  const void* no_w1   = d_in[22];
  const void* no_emb  = d_in[23];
  const void* go_w0   = d_in[24];
  const void* go_b0   = d_in[25];
  const void* go_w1   = d_in[26];
  const void* go_b1   = d_in[27];

  k_prep1<<<96,  256, 0, stream>>>(charges, etab, mp1_w0, fvec);
  k_edge <<<NN,  256, 0, stream>>>(nuclei, fvec, OFF_SA1, OFF_SB1,
                                   mp1_w0, 64*32, mp1_b0, mp1_w1, mp1_b1, OFF_MSG1);
  k_upd1 <<<192, 256, 0, stream>>>(up1_w0, up1_b0, up1_w1, up1_b1, mp2_w0, fvec);
  k_edge <<<NN,  256, 0, stream>>>(nuclei, fvec, OFF_SA2, OFF_SB2,
                                   mp2_w0, 128*32, mp2_b0, mp2_w1, mp2_b1, OFF_MSG2);
  k_upd2 <<<192, 256, 0, stream>>>(up2_w0, up2_b0, up2_w1, up2_b1,
                                   no_w0, no_b0, no_w1, no_emb,
                                   go_w0, go_b0, go_w1, go_b1,
                                   charges, fvec, d_out);
}

// Round 4
// 189.339 us; speedup vs baseline: 1.3280x; 1.2264x over previous
//
#include <hip/hip_runtime.h>
#include <hip/hip_bf16.h>

typedef __hip_bfloat16 bf16;
typedef __attribute__((ext_vector_type(8))) short short8;
typedef __attribute__((ext_vector_type(4))) float float4v;

#define NN   768
#define NEPS 767

// ---- converted fp32 constants ----
#define C_NUC   0
#define C_F     2304
#define C_ETAB  2336
#define C_MP1W0 2656
#define C_MP1B0 5728
#define C_MP1W1 5760
#define C_MP1B1 6784
#define C_UP1W0 6816
#define C_UP1B0 10912
#define C_UP1W1 10976
#define C_UP1B1 15072
#define C_MP2W0 15136
#define C_MP2B0 20256
#define C_MP2W1 20288
#define C_MP2B1 21312
#define C_UP2W0 21344
#define C_UP2B0 27488
#define C_UP2W1 27552
#define C_UP2B1 31648
#define C_NOW0  31712
#define C_NOB0  32192
#define C_NOW1  32195
#define C_NOEMB 32204
#define C_GOW0  32234
#define C_GOB0  32394
#define C_GOW1  32395
#define C_GOB1  32396
__device__ float g_c[32400];

// ---- fp32 scratch ----
#define OFF_EMB0 0
#define OFF_SA1  24576
#define OFF_SB1  49152
#define OFF_MSG1 73728
#define OFF_EMB1 98304
#define OFF_SA2  147456
#define OFF_SB2  172032
#define OFF_MSG2 196608
__device__ float g_ws[221184];
__device__ float g_agg[160];
__device__ int   g_cnt;
__device__ int   g_isf;

struct Ptrs { const void* p[28]; };

__device__ __forceinline__ float b2f(bf16 v){ return __bfloat162float(v); }
__device__ __forceinline__ float LD(const void* p, int i, int f32){
  return f32 ? ((const float*)p)[i] : b2f(((const bf16*)p)[i]);
}
__device__ __forceinline__ int detect_f32(const void* f){
  float v = ((const float*)f)[0];
  return (fabsf(v - 3.14159265f) < 0.01f) ? 1 : 0;
}
__device__ __forceinline__ float fast_rcp(float x){ return __builtin_amdgcn_rcpf(x); }
__device__ __forceinline__ float silu_f(float p){ return p * fast_rcp(1.f + __expf(-p)); }
__device__ __forceinline__ unsigned short rne_bf16(float x){
  unsigned int b = __float_as_uint(x);
  return (unsigned short)((b + 0x7fffu + ((b >> 16) & 1u)) >> 16);
}
__device__ __forceinline__ void cv(const void* p, int off, int sz, int gt, int isf){
  for (int i = gt; i < sz; i += 96*256) g_c[off + i] = LD(p, i, isf);
}

// ---------------- K1: convert all inputs to fp32 + emb0/SA1/SB1 prep ----------------
__launch_bounds__(256)
__global__ void k_conv_prep(Ptrs P, const int* __restrict__ charges){
  int t = threadIdx.x;
  int gt = blockIdx.x*256 + t;
  int isf = detect_f32(P.p[2]);
  if (gt == 0){ g_isf = isf; g_cnt = 0; }
  if (gt < 160) g_agg[gt] = 0.f;

  cv(P.p[0],  C_NUC,   2304, gt, isf);
  cv(P.p[2],  C_F,     32,   gt, isf);
  cv(P.p[3],  C_ETAB,  320,  gt, isf);
  cv(P.p[4],  C_MP1W0, 3072, gt, isf);
  cv(P.p[5],  C_MP1B0, 32,   gt, isf);
  cv(P.p[6],  C_MP1W1, 1024, gt, isf);
  cv(P.p[7],  C_MP1B1, 32,   gt, isf);
  cv(P.p[8],  C_UP1W0, 4096, gt, isf);
  cv(P.p[9],  C_UP1B0, 64,   gt, isf);
  cv(P.p[10], C_UP1W1, 4096, gt, isf);
  cv(P.p[11], C_UP1B1, 64,   gt, isf);
  cv(P.p[12], C_MP2W0, 5120, gt, isf);
  cv(P.p[13], C_MP2B0, 32,   gt, isf);
  cv(P.p[14], C_MP2W1, 1024, gt, isf);
  cv(P.p[15], C_MP2B1, 32,   gt, isf);
  cv(P.p[16], C_UP2W0, 6144, gt, isf);
  cv(P.p[17], C_UP2B0, 64,   gt, isf);
  cv(P.p[18], C_UP2W1, 4096, gt, isf);
  cv(P.p[19], C_UP2B1, 64,   gt, isf);
  cv(P.p[20], C_NOW0,  480,  gt, isf);
  cv(P.p[21], C_NOB0,  3,    gt, isf);
  cv(P.p[22], C_NOW1,  9,    gt, isf);
  cv(P.p[23], C_NOEMB, 30,   gt, isf);
  cv(P.p[24], C_GOW0,  160,  gt, isf);
  cv(P.p[25], C_GOB0,  1,    gt, isf);
  cv(P.p[26], C_GOW1,  1,    gt, isf);
  cv(P.p[27], C_GOB1,  1,    gt, isf);

  // prep: emb0 gather + SA1/SB1 (reads raw inputs, independent of conversion)
  __shared__ float w0L[2048];
  __shared__ float rowL[8][32];
  for (int idx = t; idx < 2048; idx += 256) w0L[idx] = LD(P.p[4], idx, isf);
  int nd = t >> 5, col = t & 31;
  int node = blockIdx.x*8 + nd;
  int ch = charges[node];
  float v = LD(P.p[3], ch*32 + col, isf);
  g_ws[OFF_EMB0 + node*32 + col] = v;
  rowL[nd][col] = v;
  __syncthreads();
  float sa = 0.f, sb = 0.f;
  #pragma unroll
  for (int k = 0; k < 32; k++){
    float rv = rowL[nd][k];
    sa = fmaf(rv, w0L[k*32 + col],      sa);
    sb = fmaf(rv, w0L[(32+k)*32 + col], sb);
  }
  g_ws[OFF_SA1 + node*32 + col] = sa;
  g_ws[OFF_SB1 + node*32 + col] = sb;
}

// ---------------- K2/K4: MFMA edge pass (branch-free fp32 sources) ----------------
__launch_bounds__(256)
__global__ void k_edge(int sa_off, int sb_off, int w0e_off, int b0_off,
                       int w1_off, int b1_off, int msg_off)
{
  __shared__ __align__(16) float pos[NN*3];
  __shared__ __align__(16) float w1L[1024];
  __shared__ float wsum[4][32];
  __shared__ float hsumL[32];

  int i = blockIdx.x, t = threadIdx.x;
  int w = t >> 6, lane = t & 63, q = lane >> 4, c = lane & 15;
  const float* SA = g_ws + sa_off;
  const float* SB = g_ws + sb_off;

  {
    const float4* src = (const float4*)(g_c + C_NUC);
    float4* dst = (float4*)pos;
    for (int idx = t; idx < 576; idx += 256) dst[idx] = src[idx];
    ((float4*)w1L)[t] = ((const float4*)(g_c + w1_off))[t];
  }
  short8 bf0, bf1;
  #pragma unroll
  for (int j = 0; j < 8; j++){
    int row = q*8 + j;
    bf0[j] = (short)rne_bf16(g_c[w0e_off + row*32 + c]);
    bf1[j] = (short)rne_bf16(g_c[w0e_off + row*32 + 16 + c]);
  }
  float preB0 = SA[i*32 + c]      + g_c[b0_off + c];
  float preB1 = SA[i*32 + 16 + c] + g_c[b0_off + 16 + c];
  float fj[8];
  #pragma unroll
  for (int j = 0; j < 8; j++) fj[j] = g_c[C_F + q*8 + j] * 0.1f;
  __syncthreads();

  float px = pos[i*3], py = pos[i*3+1], pz = pos[i*3+2];
  float sum0 = 0.f, sum1 = 0.f;

  for (int tl = w; tl < 48; tl += 4){
    int el = tl*16 + c;
    int ela = (el < NEPS) ? el : 0;           // dummy for el==767
    int r = ela + (ela >= i);                 // receiver = skip-self identity
    float dx = px - pos[r*3], dy = py - pos[r*3+1], dz = pz - pos[r*3+2];
    float d  = sqrtf(fmaf(dx, dx, fmaf(dy, dy, dz*dz)));
    float xs = d + 1e-8f;
    float sc = 0.44721359549995793f * fast_rcp(xs);
    short8 af;
    #pragma unroll
    for (int j = 0; j < 8; j++) af[j] = (short)rne_bf16(sc * __sinf(fj[j]*xs));

    float4v z = {0.f, 0.f, 0.f, 0.f};
    float4v a0 = __builtin_amdgcn_mfma_f32_16x16x32_bf16(af, bf0, z, 0, 0, 0);
    float4v a1 = __builtin_amdgcn_mfma_f32_16x16x32_bf16(af, bf1, z, 0, 0, 0);

    #pragma unroll
    for (int p = 0; p < 4; p++){
      int el2 = tl*16 + q*4 + p;
      if (el2 < NEPS){
        int r2 = el2 + (el2 >= i);
        float v0 = a0[p] + preB0 + SB[r2*32 + c];
        float v1 = a1[p] + preB1 + SB[r2*32 + 16 + c];
        sum0 += silu_f(v0);
        sum1 += silu_f(v1);
      }
    }
  }
  sum0 += __shfl_xor(sum0, 16); sum0 += __shfl_xor(sum0, 32);
  sum1 += __shfl_xor(sum1, 16); sum1 += __shfl_xor(sum1, 32);
  if (lane < 16){ wsum[w][lane] = sum0; wsum[w][16 + lane] = sum1; }
  __syncthreads();
  if (t < 32) hsumL[t] = wsum[0][t] + wsum[1][t] + wsum[2][t] + wsum[3][t];
  __syncthreads();
  if (t < 32){
    float y = 0.f;
    #pragma unroll
    for (int m = 0; m < 32; m++) y = fmaf(hsumL[m], w1L[m*32 + t], y);
    g_ws[msg_off + i*32 + t] = y * (1.f/767.f) + g_c[b1_off + t];
  }
}

// ---------------- K3: update MLP 1 + SA2/SB2 ----------------
__launch_bounds__(256)
__global__ void k_upd1(){
  int t = threadIdx.x;
  int nd = t >> 6, col = t & 63;
  int node = blockIdx.x*4 + nd;
  __shared__ __align__(16) float w0L[4096], w1L[4096], m2L[4096];
  __shared__ float catL[4][64], hLL[4][64], e1LL[4][64];
  {
    const float4* s0 = (const float4*)(g_c + C_UP1W0);
    const float4* s1 = (const float4*)(g_c + C_UP1W1);
    const float4* s2 = (const float4*)(g_c + C_MP2W0);
    float4* d0 = (float4*)w0L; float4* d1 = (float4*)w1L; float4* d2 = (float4*)m2L;
    #pragma unroll
    for (int rr = 0; rr < 4; rr++){
      d0[t + rr*256] = s0[t + rr*256];
      d1[t + rr*256] = s1[t + rr*256];
      d2[t + rr*256] = s2[t + rr*256];
    }
  }
  catL[nd][col] = (col < 32) ? g_ws[OFF_EMB0 + node*32 + col]
                             : g_ws[OFF_MSG1 + node*32 + col - 32];
  __syncthreads();
  float a = g_c[C_UP1B0 + col];
  #pragma unroll 8
  for (int k = 0; k < 64; k++) a = fmaf(catL[nd][k], w0L[k*64 + col], a);
  hLL[nd][col] = silu_f(a);
  __syncthreads();
  float y = g_c[C_UP1B1 + col];
  #pragma unroll 8
  for (int k = 0; k < 64; k++) y = fmaf(hLL[nd][k], w1L[k*64 + col], y);
  g_ws[OFF_EMB1 + node*64 + col] = y;
  e1LL[nd][col] = y;
  __syncthreads();
  int c32 = col & 31;
  int base = (col < 32) ? 0 : 2048;   // rows 0-63 -> SA2, rows 64-127 -> SB2
  float s2v = 0.f;
  #pragma unroll 8
  for (int k = 0; k < 64; k++) s2v = fmaf(e1LL[nd][k], m2L[base + k*32 + c32], s2v);
  if (col < 32) g_ws[OFF_SA2 + node*32 + c32] = s2v;
  else          g_ws[OFF_SB2 + node*32 + c32] = s2v;
}

// ---------------- K5: update MLP 2 + residual + node_out + global readout ----------------
__launch_bounds__(256)
__global__ void k_upd2(const int* __restrict__ charges, void* __restrict__ out){
  int t = threadIdx.x;
  int nd = t >> 6, col = t & 63;
  int node = blockIdx.x*4 + nd;
  __shared__ __align__(16) float w0L[6144], w1L[4096];
  __shared__ float noL[522];
  __shared__ float catL[4][96], hLL[4][64], aggL[4][160], h3L[4][3];
  __shared__ float red[256];
  __shared__ int lastL;
  {
    const float4* s0 = (const float4*)(g_c + C_UP2W0);
    const float4* s1 = (const float4*)(g_c + C_UP2W1);
    float4* d0 = (float4*)w0L; float4* d1 = (float4*)w1L;
    #pragma unroll
    for (int rr = 0; rr < 6; rr++) d0[t + rr*256] = s0[t + rr*256];
    #pragma unroll
    for (int rr = 0; rr < 4; rr++) d1[t + rr*256] = s1[t + rr*256];
    for (int idx = t; idx < 522; idx += 256) noL[idx] = g_c[C_NOW0 + idx];
  }
  catL[nd][col] = g_ws[OFF_EMB1 + node*64 + col];
  if (col < 32){
    catL[nd][64 + col] = g_ws[OFF_MSG2 + node*32 + col];
    aggL[nd][col]      = g_ws[OFF_EMB0 + node*32 + col];
  }
  __syncthreads();
  float a = g_c[C_UP2B0 + col];
  #pragma unroll 8
  for (int k = 0; k < 96; k++) a = fmaf(catL[nd][k], w0L[k*64 + col], a);
  hLL[nd][col] = silu_f(a);
  __syncthreads();
  float y = g_c[C_UP2B1 + col];
  #pragma unroll 8
  for (int k = 0; k < 64; k++) y = fmaf(hLL[nd][k], w1L[k*64 + col], y);
  float e2 = catL[nd][col] + y;       // residual
  aggL[nd][32 + col] = catL[nd][col]; // emb1
  aggL[nd][96 + col] = e2;            // emb2
  __syncthreads();
  if (col < 3){
    float p = noL[480 + col];
    #pragma unroll 8
    for (int k = 0; k < 160; k++) p = fmaf(aggL[nd][k], noL[k*3 + col], p);
    h3L[nd][col] = silu_f(p);
  }
  __syncthreads();
  if (col < 3){
    float o = 0.f;
    #pragma unroll
    for (int m = 0; m < 3; m++) o = fmaf(h3L[nd][m], noL[483 + m*3 + col], o);
    o += noL[492 + charges[node]*3 + col];
    int isf = g_isf;
    if (isf) ((float*)out)[node*3 + col] = o;
    else     ((bf16*)out)[node*3 + col] = __float2bfloat16(o);
  }
  if (t < 160){
    float s = aggL[0][t] + aggL[1][t] + aggL[2][t] + aggL[3][t];
    atomicAdd(&g_agg[t], s);
  }
  __threadfence();
  __syncthreads();
  if (t == 0){
    int old = atomicAdd(&g_cnt, 1);
    lastL = (old == 191) ? 1 : 0;
  }
  __syncthreads();
  if (lastL){
    float v = 0.f;
    if (t < 160) v = atomicAdd(&g_agg[t], 0.f) * (1.f/768.f) * g_c[C_GOW0 + t];
    red[t] = v;
    __syncthreads();
    if (t == 0){
      float tot = 0.f;
      for (int k = 0; k < 160; k++) tot += red[k];
      float h = silu_f(tot + g_c[C_GOB0]);
      float go = h * g_c[C_GOW1] + g_c[C_GOB1];
      if (g_isf) ((float*)out)[2304] = go;
      else       ((bf16*)out)[2304] = __float2bfloat16(go);
    }
  }
}

extern "C" void kernel_launch(void* const* d_in, const int* in_sizes, int n_in,
                              void* d_out, int out_size, void* d_ws, size_t ws_size,
                              hipStream_t stream) {
  Ptrs P;
  for (int k = 0; k < 28; k++) P.p[k] = d_in[k];
  const int* charges = (const int*)d_in[1];

  k_conv_prep<<<96, 256, 0, stream>>>(P, charges);
  k_edge<<<NN, 256, 0, stream>>>(OFF_SA1, OFF_SB1, C_MP1W0 + 64*32, C_MP1B0,
                                 C_MP1W1, C_MP1B1, OFF_MSG1);
  k_upd1<<<192, 256, 0, stream>>>();
  k_edge<<<NN, 256, 0, stream>>>(OFF_SA2, OFF_SB2, C_MP2W0 + 128*32, C_MP2B0,
                                 C_MP2W1, C_MP2B1, OFF_MSG2);
  k_upd2<<<192, 256, 0, stream>>>(charges, d_out);
}